// Round 3
// baseline (928.977 us; speedup 1.0000x reference)
//
#include <hip/hip_runtime.h>
#include <cmath>

typedef unsigned short u16;
typedef __attribute__((ext_vector_type(8))) short          bf16x8;
typedef __attribute__((ext_vector_type(8))) unsigned short u16x8;
typedef __attribute__((ext_vector_type(4))) unsigned short u16x4;
typedef __attribute__((ext_vector_type(4))) float          f32x4;
typedef __attribute__((ext_vector_type(4))) int            i32x4;

#define DEV __device__ __forceinline__
#define MFMA(a, b, c) __builtin_amdgcn_mfma_f32_16x16x32_bf16((a), (b), (c), 0, 0, 0)

DEV u16 f2bf(float f) {
    unsigned u = __float_as_uint(f);
    u = u + 0x7FFFu + ((u >> 16) & 1u);   // RNE
    return (u16)(u >> 16);
}

DEV void gload_lds16(const void* g, void* l) {
    __builtin_amdgcn_global_load_lds(
        (const __attribute__((address_space(1))) unsigned int*)g,
        (__attribute__((address_space(3))) unsigned int*)l, 16, 0, 0);
}

// ---------------------------------------------------------------- conversions
__global__ void cvt_f32_bf16(const float* __restrict__ src, u16* __restrict__ dst, int n4) {
    const int stride = gridDim.x * 256;
    for (int i = blockIdx.x * 256 + threadIdx.x; i < n4; i += stride) {
        const float4 v = ((const float4*)src)[i];
        u16x4 o = { f2bf(v.x), f2bf(v.y), f2bf(v.z), f2bf(v.w) };
        ((u16x4*)dst)[i] = o;
    }
}

__global__ void make_scale(const float* __restrict__ pds, float* __restrict__ scl) {
    int i = blockIdx.x * 256 + threadIdx.x;
    if (i >= 3072) return;
    float s;
    if (i < 1024) {
        float p  = pds[i & 63];
        float sp = log1pf(__expf(p));            // softplus
        s = 0.18033688011112042f * sp;           // D^-0.5 / ln 2
    } else if (i < 2048) {
        s = 1.8946361418776871f;                 // ln(1+e) / ln 2
    } else {
        s = 1.0f;
    }
    scl[i] = s;
}

// ---------------------------------------------------------------- big GEMM (m97 structure)
// C = A * B^T.  REQUIRES: M,N multiples of 128, K multiple of 64.
// global_load_lds width=16, linear LDS, 2-phase double-buffer.
template <int OUT_BF16>
__global__ __launch_bounds__(256, 2) void gemm_lds(const u16* __restrict__ A,
                                                   const u16* __restrict__ B,
                                                   void* __restrict__ C, int M, int N, int K,
                                                   const float* __restrict__ colscale) {
    __shared__ u16 lds[2][2][128 * 64];   // [buf][A/B] linear row-major, 64 KiB

    const int tid  = threadIdx.x;
    const int lane = tid & 63;
    const int g    = lane >> 4;
    const int cl   = lane & 15;
    const int wave = tid >> 6;
    const int wr   = wave >> 1, wc = wave & 1;
    const int m0 = blockIdx.y * 128, n0 = blockIdx.x * 128;

    const f32x4 zz = {0.f, 0.f, 0.f, 0.f};
    f32x4 acc[4][4];
#pragma unroll
    for (int i = 0; i < 4; ++i)
#pragma unroll
        for (int j = 0; j < 4; ++j) acc[i][j] = zz;

    auto stage = [&](int buf, int kt) {
        const int k0 = kt * 64;
#pragma unroll
        for (int i = 0; i < 4; ++i) {
            int c   = i * 256 + tid;          // 16B chunk id 0..1023
            int row = c >> 3, col = (c & 7) * 8;
            gload_lds16(A + (size_t)(m0 + row) * K + k0 + col, &lds[buf][0][c * 8]);
            gload_lds16(B + (size_t)(n0 + row) * K + k0 + col, &lds[buf][1][c * 8]);
        }
    };

    stage(0, 0);
    asm volatile("s_waitcnt vmcnt(0)" ::: "memory");
    __syncthreads();

    const int nkt = K >> 6;
    int cur = 0;
    for (int kt = 0; kt < nkt; ++kt) {
        if (kt + 1 < nkt) stage(cur ^ 1, kt + 1);
#pragma unroll
        for (int ks = 0; ks < 2; ++ks) {
            bf16x8 af[4], bfr[4];
#pragma unroll
            for (int i = 0; i < 4; ++i)
                af[i] = *(const bf16x8*)(&lds[cur][0][(wr * 64 + i * 16 + cl) * 64 + ks * 32 + g * 8]);
#pragma unroll
            for (int j = 0; j < 4; ++j)
                bfr[j] = *(const bf16x8*)(&lds[cur][1][(wc * 64 + j * 16 + cl) * 64 + ks * 32 + g * 8]);
#pragma unroll
            for (int i = 0; i < 4; ++i)
#pragma unroll
                for (int j = 0; j < 4; ++j) acc[i][j] = MFMA(af[i], bfr[j], acc[i][j]);
        }
        asm volatile("s_waitcnt vmcnt(0)" ::: "memory");
        __syncthreads();
        cur ^= 1;
    }

    // epilogue: C/D map: col = lane&15, row = (lane>>4)*4 + reg
#pragma unroll
    for (int i = 0; i < 4; ++i) {
#pragma unroll
        for (int j = 0; j < 4; ++j) {
            int col  = n0 + wc * 64 + j * 16 + cl;
            float sc = colscale ? colscale[col] : 1.0f;
#pragma unroll
            for (int r = 0; r < 4; ++r) {
                int row = m0 + wr * 64 + i * 16 + g * 4 + r;
                float v = acc[i][j][r] * sc;
                if (OUT_BF16)
                    ((u16*)C)[(size_t)row * N + col] = f2bf(v);
                else
                    ((float*)C)[(size_t)row * N + col] = v;
            }
        }
    }
}

// ---------------------------------------------------------------- small GEMM (bounds-checked, reg-staged)
template <int OUT_BF16>
__global__ __launch_bounds__(256, 2) void gemm_bt(const u16* __restrict__ A,
                                                  const u16* __restrict__ B,
                                                  void* __restrict__ C, int M, int N, int K,
                                                  const float* __restrict__ colscale) {
    __shared__ u16 lds[2][2][128 * 64];

    const int tid  = threadIdx.x;
    const int lane = tid & 63;
    const int g    = lane >> 4;
    const int cl   = lane & 15;
    const int wave = tid >> 6;
    const int wr   = wave >> 1, wc = wave & 1;
    const int m0 = blockIdx.y * 128, n0 = blockIdx.x * 128;

    const f32x4 zz = {0.f, 0.f, 0.f, 0.f};
    f32x4 acc[4][4];
#pragma unroll
    for (int i = 0; i < 4; ++i)
#pragma unroll
        for (int j = 0; j < 4; ++j) acc[i][j] = zz;

    const int nkt = K >> 6;
    i32x4 ra[4], rb[4];
    const i32x4 z4 = {0, 0, 0, 0};

    auto gload = [&](int kt) {
        const int k0 = kt * 64;
#pragma unroll
        for (int i = 0; i < 4; ++i) {
            int c = i * 256 + tid;
            int row = c >> 3, colb = (c & 7) * 8;
            int arow = m0 + row;
            ra[i] = (arow < M) ? *(const i32x4*)(A + (size_t)arow * K + k0 + colb) : z4;
            int brow = n0 + row;
            rb[i] = (brow < N) ? *(const i32x4*)(B + (size_t)brow * K + k0 + colb) : z4;
        }
    };
    auto sstore = [&](int buf) {
#pragma unroll
        for (int i = 0; i < 4; ++i) {
            int c = i * 256 + tid;
            int row = c >> 3;
            int sw  = (c & 7) ^ (row & 7);
            *(i32x4*)(&lds[buf][0][row * 64 + sw * 8]) = ra[i];
            *(i32x4*)(&lds[buf][1][row * 64 + sw * 8]) = rb[i];
        }
    };

    gload(0);
    sstore(0);
    __syncthreads();

    for (int kt = 0; kt < nkt; ++kt) {
        const int buf = kt & 1;
        if (kt + 1 < nkt) gload(kt + 1);
#pragma unroll
        for (int ks = 0; ks < 2; ++ks) {
            bf16x8 af[4], bfr[4];
#pragma unroll
            for (int i = 0; i < 4; ++i) {
                int row   = wr * 64 + i * 16 + cl;
                int chunk = (ks * 4 + g) ^ (row & 7);
                af[i] = *(const bf16x8*)(&lds[buf][0][row * 64 + chunk * 8]);
            }
#pragma unroll
            for (int j = 0; j < 4; ++j) {
                int row   = wc * 64 + j * 16 + cl;
                int chunk = (ks * 4 + g) ^ (row & 7);
                bfr[j] = *(const bf16x8*)(&lds[buf][1][row * 64 + chunk * 8]);
            }
#pragma unroll
            for (int i = 0; i < 4; ++i)
#pragma unroll
                for (int j = 0; j < 4; ++j) acc[i][j] = MFMA(af[i], bfr[j], acc[i][j]);
        }
        __syncthreads();
        if (kt + 1 < nkt) {
            sstore((kt + 1) & 1);
            __syncthreads();
        }
    }

#pragma unroll
    for (int i = 0; i < 4; ++i) {
#pragma unroll
        for (int j = 0; j < 4; ++j) {
            int col  = n0 + wc * 64 + j * 16 + cl;
            float sc = colscale ? colscale[col] : 1.0f;
#pragma unroll
            for (int r = 0; r < 4; ++r) {
                int row = m0 + wr * 64 + i * 16 + g * 4 + r;
                if (row < M) {
                    float v = acc[i][j][r] * sc;
                    if (OUT_BF16)
                        ((u16*)C)[(size_t)row * N + col] = f2bf(v);
                    else
                        ((float*)C)[(size_t)row * N + col] = v;
                }
            }
        }
    }
}

// ---------------------------------------------------------------- attention (unchanged, proven)
__global__ __launch_bounds__(64) void attn64(const u16* __restrict__ qkv,
                                             const u16* __restrict__ relk,
                                             u16* __restrict__ out) {
    const int bid  = blockIdx.x;
    const int h    = bid & 15;
    const int bb   = bid >> 4;
    const int b    = bb >> 8;
    const int blk  = bb & 255;
    const int lane = threadIdx.x;
    const int g    = lane >> 4;
    const int cl   = lane & 15;

    __shared__ u16   Vt[64][104];
    __shared__ float AC[32][81];
    __shared__ float BD[32][81];
    __shared__ u16   P[32][104];

    const size_t base  = (size_t)b * 8192;
    const int    ctx0  = blk * 32 - 31;
    const size_t qrow0 = base + (size_t)blk * 32;

    for (int i = lane; i < 32 * 81; i += 64) (&BD[0][0])[i] = 0.f;

    for (int l = lane; l < 96; l += 64) {
        int sr = ctx0 + l;
        if (l < 71 && sr >= 0 && sr < 8192) {
            const u16* vp = qkv + (base + sr) * 3072 + 2048 + h * 64;
#pragma unroll
            for (int d8 = 0; d8 < 8; ++d8) {
                u16x8 v = *(const u16x8*)(vp + d8 * 8);
#pragma unroll
                for (int e = 0; e < 8; ++e) Vt[d8 * 8 + e][l] = v[e];
            }
        } else {
#pragma unroll
            for (int d = 0; d < 64; ++d) Vt[d][l] = 0;
        }
    }

    bf16x8 qf[2][2];
#pragma unroll
    for (int mi = 0; mi < 2; ++mi)
#pragma unroll
        for (int ks = 0; ks < 2; ++ks)
            qf[mi][ks] = *(const bf16x8*)(qkv + (qrow0 + mi * 16 + cl) * 3072 + h * 64 + ks * 32 + g * 8);

    __syncthreads();

    const bf16x8 z8 = {0, 0, 0, 0, 0, 0, 0, 0};
    const f32x4  zz = {0.f, 0.f, 0.f, 0.f};

#pragma unroll
    for (int nt = 0; nt < 5; ++nt) {
        f32x4 a0 = zz, a1 = zz, p0 = zz, p1 = zz;
        const int l  = nt * 16 + cl;
        const int sr = ctx0 + l;
        const bool kv = (l < 71) && (sr >= 0) && (sr < 8192);
        const bool rv = (l < 71);
#pragma unroll
        for (int ks = 0; ks < 2; ++ks) {
            bf16x8 kf = kv ? *(const bf16x8*)(qkv + (base + sr) * 3072 + 1024 + h * 64 + ks * 32 + g * 8) : z8;
            bf16x8 rf = rv ? *(const bf16x8*)(relk + (size_t)l * 1024 + h * 64 + ks * 32 + g * 8) : z8;
            a0 = MFMA(qf[0][ks], kf, a0);
            a1 = MFMA(qf[1][ks], kf, a1);
            p0 = MFMA(qf[0][ks], rf, p0);
            p1 = MFMA(qf[1][ks], rf, p1);
        }
#pragma unroll
        for (int r = 0; r < 4; ++r) {
            AC[g * 4 + r][l]      = a0[r];
            AC[16 + g * 4 + r][l] = a1[r];
        }
        if (l < 71) {
#pragma unroll
            for (int r = 0; r < 4; ++r) {
#pragma unroll
                for (int mi = 0; mi < 2; ++mi) {
                    int   c = mi * 16 + g * 4 + r;
                    float v = mi ? p1[r] : p0[r];
                    int   s = l + c;
                    int  cp = (s <= 70) ? c : c + 1;
                    int   j = (s <= 70) ? s : s - 71;
                    if (cp < 32) BD[cp][j] = v;
                }
            }
        }
    }
    __syncthreads();

    if (lane < 32) {
        const int c = lane;
        float m = -1e30f;
#pragma unroll
        for (int j = 0; j < 71; ++j) {
            float lg = tanhf((AC[c][j] + BD[c][j]) * 0.02f) * 50.f;
            AC[c][j] = lg;
            m = fmaxf(m, lg);
        }
        float s = 0.f;
#pragma unroll
        for (int j = 0; j < 71; ++j) {
            float e = __expf(AC[c][j] - m);
            AC[c][j] = e;
            s += e;
        }
        float inv = 1.f / s;
#pragma unroll
        for (int j = 0; j < 71; ++j) P[c][j] = f2bf(AC[c][j] * inv);
#pragma unroll
        for (int j = 71; j < 96; ++j) P[c][j] = 0;
    }
    __syncthreads();

    f32x4 o[2][4];
#pragma unroll
    for (int mt = 0; mt < 2; ++mt)
#pragma unroll
        for (int nt = 0; nt < 4; ++nt) o[mt][nt] = zz;

#pragma unroll
    for (int ks = 0; ks < 3; ++ks) {
        bf16x8 pf[2], vf[4];
#pragma unroll
        for (int mt = 0; mt < 2; ++mt) pf[mt] = *(const bf16x8*)(&P[mt * 16 + cl][ks * 32 + g * 8]);
#pragma unroll
        for (int nt = 0; nt < 4; ++nt) vf[nt] = *(const bf16x8*)(&Vt[nt * 16 + cl][ks * 32 + g * 8]);
#pragma unroll
        for (int mt = 0; mt < 2; ++mt)
#pragma unroll
            for (int nt = 0; nt < 4; ++nt) o[mt][nt] = MFMA(pf[mt], vf[nt], o[mt][nt]);
    }

    u16* op = out + qrow0 * 1024 + h * 64;
#pragma unroll
    for (int mt = 0; mt < 2; ++mt)
#pragma unroll
        for (int nt = 0; nt < 4; ++nt)
#pragma unroll
            for (int r = 0; r < 4; ++r)
                op[(size_t)(mt * 16 + g * 4 + r) * 1024 + nt * 16 + cl] = f2bf(o[mt][nt][r]);
}

// ---------------------------------------------------------------- launcher
extern "C" void kernel_launch(void* const* d_in, const int* in_sizes, int n_in,
                              void* d_out, int out_size, void* d_ws, size_t ws_size,
                              hipStream_t stream) {
    const float* hs    = (const float*)d_in[0];
    const float* pe    = (const float*)d_in[1];
    const float* wq    = (const float*)d_in[2];
    const float* wk    = (const float*)d_in[3];
    const float* wv    = (const float*)d_in[4];
    const float* wrel  = (const float*)d_in[5];
    const float* wpost = (const float*)d_in[6];
    const float* pds   = (const float*)d_in[7];

    char* w = (char*)d_ws;
    u16* Xb     = (u16*)w;  w += (size_t)32768 * 1024 * 2;
    u16* Wcat   = (u16*)w;  w += (size_t)3072 * 1024 * 2;
    u16* Wrelb  = (u16*)w;  w += (size_t)1024 * 1024 * 2;
    u16* Wpostb = (u16*)w;  w += (size_t)1024 * 1024 * 2;
    u16* PEb    = (u16*)w;  w += (size_t)71 * 1024 * 2 + 512;
    float* scl  = (float*)w; w += 3072 * 4;
    u16* QKV    = (u16*)w;  w += (size_t)32768 * 3072 * 2;
    u16* RELK   = (u16*)w;  w += (size_t)71 * 1024 * 2 + 512;
    u16* AOUT   = Xb;   // Xb dead after QKV GEMM

    cvt_f32_bf16<<<2048, 256, 0, stream>>>(hs, Xb, 8388608);
    cvt_f32_bf16<<<512, 256, 0, stream>>>(wq, Wcat, 262144);
    cvt_f32_bf16<<<512, 256, 0, stream>>>(wk, Wcat + 1048576, 262144);
    cvt_f32_bf16<<<512, 256, 0, stream>>>(wv, Wcat + 2097152, 262144);
    cvt_f32_bf16<<<512, 256, 0, stream>>>(wrel, Wrelb, 262144);
    cvt_f32_bf16<<<512, 256, 0, stream>>>(wpost, Wpostb, 262144);
    cvt_f32_bf16<<<71, 256, 0, stream>>>(pe, PEb, 18176);
    make_scale<<<12, 256, 0, stream>>>(pds, scl);

    dim3 blk256(256);
    gemm_lds<1><<<dim3(24, 256), blk256, 0, stream>>>(Xb, Wcat, QKV, 32768, 3072, 1024, scl);
    gemm_bt<1><<<dim3(8, 1), blk256, 0, stream>>>(PEb, Wrelb, RELK, 71, 1024, 1024, nullptr);
    attn64<<<16384, 64, 0, stream>>>(QKV, RELK, AOUT);
    gemm_lds<0><<<dim3(8, 256), blk256, 0, stream>>>(AOUT, Wpostb, d_out, 32768, 1024, 1024, nullptr);
}

// Round 7
// 919.131 us; speedup vs baseline: 1.0107x; 1.0107x over previous
//
#include <hip/hip_runtime.h>
#include <cmath>

typedef unsigned short u16;
typedef __attribute__((ext_vector_type(8))) short          bf16x8;
typedef __attribute__((ext_vector_type(8))) unsigned short u16x8;
typedef __attribute__((ext_vector_type(4))) unsigned short u16x4;
typedef __attribute__((ext_vector_type(4))) float          f32x4;
typedef __attribute__((ext_vector_type(4))) int            i32x4;

#define DEV __device__ __forceinline__
#define MFMA(a, b, c) __builtin_amdgcn_mfma_f32_16x16x32_bf16((a), (b), (c), 0, 0, 0)

DEV u16 f2bf(float f) {
    unsigned u = __float_as_uint(f);
    u = u + 0x7FFFu + ((u >> 16) & 1u);   // RNE
    return (u16)(u >> 16);
}

DEV void gload_lds16(const void* g, void* l) {
    __builtin_amdgcn_global_load_lds(
        (const __attribute__((address_space(1))) unsigned int*)g,
        (__attribute__((address_space(3))) unsigned int*)l, 16, 0, 0);
}

// ---------------------------------------------------------------- conversions
__global__ void cvt_f32_bf16(const float* __restrict__ src, u16* __restrict__ dst, int n4) {
    const int stride = gridDim.x * 256;
    for (int i = blockIdx.x * 256 + threadIdx.x; i < n4; i += stride) {
        const float4 v = ((const float4*)src)[i];
        u16x4 o = { f2bf(v.x), f2bf(v.y), f2bf(v.z), f2bf(v.w) };
        ((u16x4*)dst)[i] = o;
    }
}

__global__ void make_scale(const float* __restrict__ pds, float* __restrict__ scl) {
    int i = blockIdx.x * 256 + threadIdx.x;
    if (i >= 3072) return;
    float s;
    if (i < 1024) {
        float p  = pds[i & 63];
        float sp = log1pf(__expf(p));            // softplus
        s = 0.18033688011112042f * sp;           // D^-0.5 / ln 2
    } else if (i < 2048) {
        s = 1.8946361418776871f;                 // ln(1+e) / ln 2
    } else {
        s = 1.0f;
    }
    scl[i] = s;
}

// ---------------------------------------------------------------- big GEMM
// C = A * B^T.  REQUIRES: M,N multiples of 128, K multiple of 64.
// global_load_lds width=16, LINEAR LDS dest + pre-swizzled GLOBAL source,
// XOR-swizzled ds_read (rule #21: both-sides involution).
template <int OUT_BF16>
__global__ __launch_bounds__(256, 2) void gemm_lds(const u16* __restrict__ A,
                                                   const u16* __restrict__ B,
                                                   void* __restrict__ C, int M, int N, int K,
                                                   const float* __restrict__ colscale) {
    __shared__ u16 lds[2][2][128 * 64];   // [buf][A/B] linear, 64 KiB

    const int tid  = threadIdx.x;
    const int lane = tid & 63;
    const int g    = lane >> 4;
    const int cl   = lane & 15;
    const int wave = tid >> 6;
    const int wr   = wave >> 1, wc = wave & 1;
    const int m0 = blockIdx.y * 128, n0 = blockIdx.x * 128;

    const f32x4 zz = {0.f, 0.f, 0.f, 0.f};
    f32x4 acc[4][4];
#pragma unroll
    for (int i = 0; i < 4; ++i)
#pragma unroll
        for (int j = 0; j < 4; ++j) acc[i][j] = zz;

    auto stage = [&](int buf, int kt) {
        const int k0 = kt * 64;
#pragma unroll
        for (int i = 0; i < 4; ++i) {
            int c   = i * 256 + tid;              // 16B chunk id 0..1023
            int row = c >> 3;
            int sw  = (c & 7) ^ (row & 7);        // swizzle SOURCE column chunk
            gload_lds16(A + (size_t)(m0 + row) * K + k0 + sw * 8, &lds[buf][0][c * 8]);
            gload_lds16(B + (size_t)(n0 + row) * K + k0 + sw * 8, &lds[buf][1][c * 8]);
        }
    };

    stage(0, 0);
    asm volatile("s_waitcnt vmcnt(0)" ::: "memory");
    __syncthreads();

    const int nkt = K >> 6;
    int cur = 0;
    for (int kt = 0; kt < nkt; ++kt) {
        if (kt + 1 < nkt) stage(cur ^ 1, kt + 1);
#pragma unroll
        for (int ks = 0; ks < 2; ++ks) {
            bf16x8 af[4], bfr[4];
#pragma unroll
            for (int i = 0; i < 4; ++i) {
                int row   = wr * 64 + i * 16 + cl;
                int chunk = (ks * 4 + g) ^ (row & 7);   // matching read swizzle
                af[i] = *(const bf16x8*)(&lds[cur][0][row * 64 + chunk * 8]);
            }
#pragma unroll
            for (int j = 0; j < 4; ++j) {
                int row   = wc * 64 + j * 16 + cl;
                int chunk = (ks * 4 + g) ^ (row & 7);
                bfr[j] = *(const bf16x8*)(&lds[cur][1][row * 64 + chunk * 8]);
            }
#pragma unroll
            for (int i = 0; i < 4; ++i)
#pragma unroll
                for (int j = 0; j < 4; ++j) acc[i][j] = MFMA(af[i], bfr[j], acc[i][j]);
        }
        asm volatile("s_waitcnt vmcnt(0)" ::: "memory");
        __syncthreads();
        cur ^= 1;
    }

    // epilogue: C/D map: col = lane&15, row = (lane>>4)*4 + reg
#pragma unroll
    for (int i = 0; i < 4; ++i) {
#pragma unroll
        for (int j = 0; j < 4; ++j) {
            int col  = n0 + wc * 64 + j * 16 + cl;
            float sc = colscale ? colscale[col] : 1.0f;
#pragma unroll
            for (int r = 0; r < 4; ++r) {
                int row = m0 + wr * 64 + i * 16 + g * 4 + r;
                float v = acc[i][j][r] * sc;
                if (OUT_BF16)
                    ((u16*)C)[(size_t)row * N + col] = f2bf(v);
                else
                    ((float*)C)[(size_t)row * N + col] = v;
            }
        }
    }
}

// ---------------------------------------------------------------- small GEMM (bounds-checked, reg-staged)
template <int OUT_BF16>
__global__ __launch_bounds__(256, 2) void gemm_bt(const u16* __restrict__ A,
                                                  const u16* __restrict__ B,
                                                  void* __restrict__ C, int M, int N, int K,
                                                  const float* __restrict__ colscale) {
    __shared__ u16 lds[2][2][128 * 64];

    const int tid  = threadIdx.x;
    const int lane = tid & 63;
    const int g    = lane >> 4;
    const int cl   = lane & 15;
    const int wave = tid >> 6;
    const int wr   = wave >> 1, wc = wave & 1;
    const int m0 = blockIdx.y * 128, n0 = blockIdx.x * 128;

    const f32x4 zz = {0.f, 0.f, 0.f, 0.f};
    f32x4 acc[4][4];
#pragma unroll
    for (int i = 0; i < 4; ++i)
#pragma unroll
        for (int j = 0; j < 4; ++j) acc[i][j] = zz;

    const int nkt = K >> 6;
    i32x4 ra[4], rb[4];
    const i32x4 z4 = {0, 0, 0, 0};

    auto gload = [&](int kt) {
        const int k0 = kt * 64;
#pragma unroll
        for (int i = 0; i < 4; ++i) {
            int c = i * 256 + tid;
            int row = c >> 3, colb = (c & 7) * 8;
            int arow = m0 + row;
            ra[i] = (arow < M) ? *(const i32x4*)(A + (size_t)arow * K + k0 + colb) : z4;
            int brow = n0 + row;
            rb[i] = (brow < N) ? *(const i32x4*)(B + (size_t)brow * K + k0 + colb) : z4;
        }
    };
    auto sstore = [&](int buf) {
#pragma unroll
        for (int i = 0; i < 4; ++i) {
            int c = i * 256 + tid;
            int row = c >> 3;
            int sw  = (c & 7) ^ (row & 7);
            *(i32x4*)(&lds[buf][0][row * 64 + sw * 8]) = ra[i];
            *(i32x4*)(&lds[buf][1][row * 64 + sw * 8]) = rb[i];
        }
    };

    gload(0);
    sstore(0);
    __syncthreads();

    for (int kt = 0; kt < nkt; ++kt) {
        const int buf = kt & 1;
        if (kt + 1 < nkt) gload(kt + 1);
#pragma unroll
        for (int ks = 0; ks < 2; ++ks) {
            bf16x8 af[4], bfr[4];
#pragma unroll
            for (int i = 0; i < 4; ++i) {
                int row   = wr * 64 + i * 16 + cl;
                int chunk = (ks * 4 + g) ^ (row & 7);
                af[i] = *(const bf16x8*)(&lds[buf][0][row * 64 + chunk * 8]);
            }
#pragma unroll
            for (int j = 0; j < 4; ++j) {
                int row   = wc * 64 + j * 16 + cl;
                int chunk = (ks * 4 + g) ^ (row & 7);
                bfr[j] = *(const bf16x8*)(&lds[buf][1][row * 64 + chunk * 8]);
            }
#pragma unroll
            for (int i = 0; i < 4; ++i)
#pragma unroll
                for (int j = 0; j < 4; ++j) acc[i][j] = MFMA(af[i], bfr[j], acc[i][j]);
        }
        __syncthreads();
        if (kt + 1 < nkt) {
            sstore((kt + 1) & 1);
            __syncthreads();
        }
    }

#pragma unroll
    for (int i = 0; i < 4; ++i) {
#pragma unroll
        for (int j = 0; j < 4; ++j) {
            int col  = n0 + wc * 64 + j * 16 + cl;
            float sc = colscale ? colscale[col] : 1.0f;
#pragma unroll
            for (int r = 0; r < 4; ++r) {
                int row = m0 + wr * 64 + i * 16 + g * 4 + r;
                if (row < M) {
                    float v = acc[i][j][r] * sc;
                    if (OUT_BF16)
                        ((u16*)C)[(size_t)row * N + col] = f2bf(v);
                    else
                        ((float*)C)[(size_t)row * N + col] = v;
                }
            }
        }
    }
}

// ---------------------------------------------------------------- attention (unchanged, proven)
__global__ __launch_bounds__(64) void attn64(const u16* __restrict__ qkv,
                                             const u16* __restrict__ relk,
                                             u16* __restrict__ out) {
    const int bid  = blockIdx.x;
    const int h    = bid & 15;
    const int bb   = bid >> 4;
    const int b    = bb >> 8;
    const int blk  = bb & 255;
    const int lane = threadIdx.x;
    const int g    = lane >> 4;
    const int cl   = lane & 15;

    __shared__ u16   Vt[64][104];
    __shared__ float AC[32][81];
    __shared__ float BD[32][81];
    __shared__ u16   P[32][104];

    const size_t base  = (size_t)b * 8192;
    const int    ctx0  = blk * 32 - 31;
    const size_t qrow0 = base + (size_t)blk * 32;

    for (int i = lane; i < 32 * 81; i += 64) (&BD[0][0])[i] = 0.f;

    for (int l = lane; l < 96; l += 64) {
        int sr = ctx0 + l;
        if (l < 71 && sr >= 0 && sr < 8192) {
            const u16* vp = qkv + (base + sr) * 3072 + 2048 + h * 64;
#pragma unroll
            for (int d8 = 0; d8 < 8; ++d8) {
                u16x8 v = *(const u16x8*)(vp + d8 * 8);
#pragma unroll
                for (int e = 0; e < 8; ++e) Vt[d8 * 8 + e][l] = v[e];
            }
        } else {
#pragma unroll
            for (int d = 0; d < 64; ++d) Vt[d][l] = 0;
        }
    }

    bf16x8 qf[2][2];
#pragma unroll
    for (int mi = 0; mi < 2; ++mi)
#pragma unroll
        for (int ks = 0; ks < 2; ++ks)
            qf[mi][ks] = *(const bf16x8*)(qkv + (qrow0 + mi * 16 + cl) * 3072 + h * 64 + ks * 32 + g * 8);

    __syncthreads();

    const bf16x8 z8 = {0, 0, 0, 0, 0, 0, 0, 0};
    const f32x4  zz = {0.f, 0.f, 0.f, 0.f};

#pragma unroll
    for (int nt = 0; nt < 5; ++nt) {
        f32x4 a0 = zz, a1 = zz, p0 = zz, p1 = zz;
        const int l  = nt * 16 + cl;
        const int sr = ctx0 + l;
        const bool kv = (l < 71) && (sr >= 0) && (sr < 8192);
        const bool rv = (l < 71);
#pragma unroll
        for (int ks = 0; ks < 2; ++ks) {
            bf16x8 kf = kv ? *(const bf16x8*)(qkv + (base + sr) * 3072 + 1024 + h * 64 + ks * 32 + g * 8) : z8;
            bf16x8 rf = rv ? *(const bf16x8*)(relk + (size_t)l * 1024 + h * 64 + ks * 32 + g * 8) : z8;
            a0 = MFMA(qf[0][ks], kf, a0);
            a1 = MFMA(qf[1][ks], kf, a1);
            p0 = MFMA(qf[0][ks], rf, p0);
            p1 = MFMA(qf[1][ks], rf, p1);
        }
#pragma unroll
        for (int r = 0; r < 4; ++r) {
            AC[g * 4 + r][l]      = a0[r];
            AC[16 + g * 4 + r][l] = a1[r];
        }
        if (l < 71) {
#pragma unroll
            for (int r = 0; r < 4; ++r) {
#pragma unroll
                for (int mi = 0; mi < 2; ++mi) {
                    int   c = mi * 16 + g * 4 + r;
                    float v = mi ? p1[r] : p0[r];
                    int   s = l + c;
                    int  cp = (s <= 70) ? c : c + 1;
                    int   j = (s <= 70) ? s : s - 71;
                    if (cp < 32) BD[cp][j] = v;
                }
            }
        }
    }
    __syncthreads();

    if (lane < 32) {
        const int c = lane;
        float m = -1e30f;
#pragma unroll
        for (int j = 0; j < 71; ++j) {
            float lg = tanhf((AC[c][j] + BD[c][j]) * 0.02f) * 50.f;
            AC[c][j] = lg;
            m = fmaxf(m, lg);
        }
        float s = 0.f;
#pragma unroll
        for (int j = 0; j < 71; ++j) {
            float e = __expf(AC[c][j] - m);
            AC[c][j] = e;
            s += e;
        }
        float inv = 1.f / s;
#pragma unroll
        for (int j = 0; j < 71; ++j) P[c][j] = f2bf(AC[c][j] * inv);
#pragma unroll
        for (int j = 71; j < 96; ++j) P[c][j] = 0;
    }
    __syncthreads();

    f32x4 o[2][4];
#pragma unroll
    for (int mt = 0; mt < 2; ++mt)
#pragma unroll
        for (int nt = 0; nt < 4; ++nt) o[mt][nt] = zz;

#pragma unroll
    for (int ks = 0; ks < 3; ++ks) {
        bf16x8 pf[2], vf[4];
#pragma unroll
        for (int mt = 0; mt < 2; ++mt) pf[mt] = *(const bf16x8*)(&P[mt * 16 + cl][ks * 32 + g * 8]);
#pragma unroll
        for (int nt = 0; nt < 4; ++nt) vf[nt] = *(const bf16x8*)(&Vt[nt * 16 + cl][ks * 32 + g * 8]);
#pragma unroll
        for (int mt = 0; mt < 2; ++mt)
#pragma unroll
            for (int nt = 0; nt < 4; ++nt) o[mt][nt] = MFMA(pf[mt], vf[nt], o[mt][nt]);
    }

    u16* op = out + qrow0 * 1024 + h * 64;
#pragma unroll
    for (int mt = 0; mt < 2; ++mt)
#pragma unroll
        for (int nt = 0; nt < 4; ++nt)
#pragma unroll
            for (int r = 0; r < 4; ++r)
                op[(size_t)(mt * 16 + g * 4 + r) * 1024 + nt * 16 + cl] = f2bf(o[mt][nt][r]);
}

// ---------------------------------------------------------------- launcher
extern "C" void kernel_launch(void* const* d_in, const int* in_sizes, int n_in,
                              void* d_out, int out_size, void* d_ws, size_t ws_size,
                              hipStream_t stream) {
    const float* hs    = (const float*)d_in[0];
    const float* pe    = (const float*)d_in[1];
    const float* wq    = (const float*)d_in[2];
    const float* wk    = (const float*)d_in[3];
    const float* wv    = (const float*)d_in[4];
    const float* wrel  = (const float*)d_in[5];
    const float* wpost = (const float*)d_in[6];
    const float* pds   = (const float*)d_in[7];

    char* w = (char*)d_ws;
    u16* Xb     = (u16*)w;  w += (size_t)32768 * 1024 * 2;
    u16* Wcat   = (u16*)w;  w += (size_t)3072 * 1024 * 2;
    u16* Wrelb  = (u16*)w;  w += (size_t)1024 * 1024 * 2;
    u16* Wpostb = (u16*)w;  w += (size_t)1024 * 1024 * 2;
    u16* PEb    = (u16*)w;  w += (size_t)71 * 1024 * 2 + 512;
    float* scl  = (float*)w; w += 3072 * 4;
    u16* QKV    = (u16*)w;  w += (size_t)32768 * 3072 * 2;
    u16* RELK   = (u16*)w;  w += (size_t)71 * 1024 * 2 + 512;
    u16* AOUT   = Xb;   // Xb dead after QKV GEMM

    cvt_f32_bf16<<<2048, 256, 0, stream>>>(hs, Xb, 8388608);
    cvt_f32_bf16<<<512, 256, 0, stream>>>(wq, Wcat, 262144);
    cvt_f32_bf16<<<512, 256, 0, stream>>>(wk, Wcat + 1048576, 262144);
    cvt_f32_bf16<<<512, 256, 0, stream>>>(wv, Wcat + 2097152, 262144);
    cvt_f32_bf16<<<512, 256, 0, stream>>>(wrel, Wrelb, 262144);
    cvt_f32_bf16<<<512, 256, 0, stream>>>(wpost, Wpostb, 262144);
    cvt_f32_bf16<<<71, 256, 0, stream>>>(pe, PEb, 18176);
    make_scale<<<12, 256, 0, stream>>>(pds, scl);

    dim3 blk256(256);
    gemm_lds<1><<<dim3(24, 256), blk256, 0, stream>>>(Xb, Wcat, QKV, 32768, 3072, 1024, scl);
    gemm_bt<1><<<dim3(8, 1), blk256, 0, stream>>>(PEb, Wrelb, RELK, 71, 1024, 1024, nullptr);
    attn64<<<16384, 64, 0, stream>>>(QKV, RELK, AOUT);
    gemm_lds<0><<<dim3(8, 256), blk256, 0, stream>>>(AOUT, Wpostb, d_out, 32768, 1024, 1024, nullptr);
}